// Round 1
// baseline (159.537 us; speedup 1.0000x reference)
//
#include <hip/hip_runtime.h>
#include <math.h>

#define HDIM 768
#define DD 64
#define SEQL 1024
#define NH 12
#define NB 8

// ---------------- Kernel 1: seq = hidden@W1+b1, RoPE(q,k), bias = seq@W2+b2 ----------------
// 512 blocks x 128 threads; each block does 16 rows of the 8192-row problem.
__global__ __launch_bounds__(128) void k1_seq_rope_bias(
    const float* __restrict__ hidden, const float* __restrict__ W1,
    const float* __restrict__ b1, const float* __restrict__ W2,
    const float* __restrict__ b2,
    float* __restrict__ qo, float* __restrict__ ko,
    float* __restrict__ bqo, float* __restrict__ bko)
{
    __shared__ float hs[16 * HDIM];   // 48 KB: 16 hidden rows
    __shared__ float sq[16][132];     // seq tile (pad 132 for banks)
    const int tid = threadIdx.x;
    const long row0 = (long)blockIdx.x * 16;

    // stage 16 hidden rows (coalesced float4)
    const float4* src = (const float4*)(hidden + row0 * HDIM);
    float4* hdst = (float4*)hs;
    #pragma unroll
    for (int t = 0; t < 24; ++t)
        hdst[tid + t * 128] = src[tid + t * 128];
    __syncthreads();

    // GEMM: thread = 4 rows x 4 cols. cx in [0,32) -> cols 4cx.. ; ry in [0,4) -> rows 4ry..
    const int cx = tid & 31;
    const int ry = tid >> 5;
    const float4 bias1 = ((const float4*)b1)[cx];
    float4 acc[4];
    #pragma unroll
    for (int r = 0; r < 4; ++r) acc[r] = bias1;

    for (int k4 = 0; k4 < HDIM / 4; ++k4) {
        float4 w[4];
        #pragma unroll
        for (int kk = 0; kk < 4; ++kk)
            w[kk] = *(const float4*)(W1 + (k4 * 4 + kk) * 128 + cx * 4);
        #pragma unroll
        for (int r = 0; r < 4; ++r) {
            float4 hv = *(const float4*)(hs + (ry * 4 + r) * HDIM + k4 * 4);
            acc[r].x = fmaf(hv.x, w[0].x, fmaf(hv.y, w[1].x, fmaf(hv.z, w[2].x, fmaf(hv.w, w[3].x, acc[r].x))));
            acc[r].y = fmaf(hv.x, w[0].y, fmaf(hv.y, w[1].y, fmaf(hv.z, w[2].y, fmaf(hv.w, w[3].y, acc[r].y))));
            acc[r].z = fmaf(hv.x, w[0].z, fmaf(hv.y, w[1].z, fmaf(hv.z, w[2].z, fmaf(hv.w, w[3].z, acc[r].z))));
            acc[r].w = fmaf(hv.x, w[0].w, fmaf(hv.y, w[1].w, fmaf(hv.z, w[2].w, fmaf(hv.w, w[3].w, acc[r].w))));
        }
    }
    #pragma unroll
    for (int r = 0; r < 4; ++r)
        *(float4*)&sq[ry * 4 + r][cx * 4] = acc[r];
    __syncthreads();

    // bias: 16 rows x 24 outputs, dot over 128
    for (int idx = tid; idx < 16 * 24; idx += 128) {
        int r = idx / 24, jj = idx - r * 24;
        float s = b2[jj];
        #pragma unroll 16
        for (int c = 0; c < 128; ++c)
            s = fmaf(sq[r][c], W2[c * 24 + jj], s);
        long grow = row0 + r;
        if (jj & 1) bko[grow * NH + (jj >> 1)] = s;
        else        bqo[grow * NH + (jj >> 1)] = s;
    }

    // RoPE: 16 rows x 32 pairs, q and k share sincos
    for (int idx = tid; idx < 16 * 32; idx += 128) {
        int r = idx >> 5, p = idx & 31;
        long grow = row0 + r;
        int pos = (int)(grow & (SEQL - 1));
        float inv = __expf((float)p * -0.28782313662425576f); // 10000^(-p/32)
        float ang = (float)pos * inv;
        float sn, cs;
        __sincosf(ang, &sn, &cs);
        long base = grow * DD;
        float x0 = sq[r][2 * p], x1 = sq[r][2 * p + 1];
        qo[base + 2 * p]     = x0 * cs - x1 * sn;
        qo[base + 2 * p + 1] = x1 * cs + x0 * sn;
        float y0 = sq[r][DD + 2 * p], y1 = sq[r][DD + 2 * p + 1];
        ko[base + 2 * p]     = y0 * cs - y1 * sn;
        ko[base + 2 * p + 1] = y1 * cs + y0 * sn;
    }
}

// ---------------- Kernel 2: logits[b,h,m,n] = q.k/8 + bq[h,m] + bk[h,n] - tri - mask ----------------
// grid (16 n-tiles, 8 m-tiles, 8 b) x 256 threads. Tile 128(m) x 64(n), qk computed once, 12 heads fanned out.
__global__ __launch_bounds__(256, 2) void k2_logits(
    const float* __restrict__ q, const float* __restrict__ kmat,
    const float* __restrict__ bq, const float* __restrict__ bk,
    const int* __restrict__ mask, float* __restrict__ out)
{
    __shared__ float qs[128][68];  // 34.8 KB (pad 68: row stride 4 banks -> conflict-free strided reads)
    __shared__ float ks[64][68];   // 17.4 KB
    const int tid = threadIdx.x;
    const int b = blockIdx.z;
    const int m0 = blockIdx.y * 128;
    const int n0 = blockIdx.x * 64;

    const float4* qsrc = (const float4*)(q + ((long)b * SEQL + m0) * DD);
    #pragma unroll
    for (int t = 0; t < 8; ++t) {
        int idx = tid + t * 256;
        *(float4*)&qs[idx >> 4][(idx & 15) * 4] = qsrc[idx];
    }
    const float4* ksrc = (const float4*)(kmat + ((long)b * SEQL + n0) * DD);
    #pragma unroll
    for (int t = 0; t < 4; ++t) {
        int idx = tid + t * 256;
        *(float4*)&ks[idx >> 4][(idx & 15) * 4] = ksrc[idx];
    }
    __syncthreads();

    const int tm = tid >> 4;  // m = tm + 16*i  (i<8)
    const int tn = tid & 15;  // n = tn + 16*j  (j<4)
    float acc[8][4];
    #pragma unroll
    for (int i = 0; i < 8; ++i)
        #pragma unroll
        for (int j = 0; j < 4; ++j) acc[i][j] = 0.f;

    #pragma unroll
    for (int k4 = 0; k4 < 16; ++k4) {
        float4 kv[4];
        #pragma unroll
        for (int j = 0; j < 4; ++j)
            kv[j] = *(const float4*)&ks[tn + 16 * j][k4 * 4];
        #pragma unroll
        for (int i = 0; i < 8; ++i) {
            float4 qv = *(const float4*)&qs[tm + 16 * i][k4 * 4];
            #pragma unroll
            for (int j = 0; j < 4; ++j)
                acc[i][j] = fmaf(qv.x, kv[j].x, fmaf(qv.y, kv[j].y,
                             fmaf(qv.z, kv[j].z, fmaf(qv.w, kv[j].w, acc[i][j]))));
        }
    }

    // masks + scale + causal tri, folded into acc
    int mm[8], mn[4];
    #pragma unroll
    for (int i = 0; i < 8; ++i) mm[i] = mask[b * SEQL + m0 + tm + 16 * i];
    #pragma unroll
    for (int j = 0; j < 4; ++j) mn[j] = mask[b * SEQL + n0 + tn + 16 * j];
    #pragma unroll
    for (int i = 0; i < 8; ++i) {
        int m = m0 + tm + 16 * i;
        #pragma unroll
        for (int j = 0; j < 4; ++j) {
            int n = n0 + tn + 16 * j;
            float v = acc[i][j] * 0.125f;
            if (m > n) v -= 1e12f;
            if (!(mm[i] && mn[j])) v = -INFINITY;
            acc[i][j] = v;
        }
    }

    // fan out to 12 heads
    #pragma unroll 1
    for (int h = 0; h < NH; ++h) {
        float bkv[4];
        #pragma unroll
        for (int j = 0; j < 4; ++j)
            bkv[j] = bk[(long)(b * SEQL + n0 + tn + 16 * j) * NH + h];
        float* ob = out + ((long)(b * NH + h) * SEQL + m0) * SEQL + n0 + tn;
        #pragma unroll
        for (int i = 0; i < 8; ++i) {
            float bqv = bq[(long)(b * SEQL + m0 + tm + 16 * i) * NH + h];
            float* rp = ob + (long)(tm + 16 * i) * SEQL;
            #pragma unroll
            for (int j = 0; j < 4; ++j)
                rp[16 * j] = acc[i][j] + bqv + bkv[j];
        }
    }
}

extern "C" void kernel_launch(void* const* d_in, const int* in_sizes, int n_in,
                              void* d_out, int out_size, void* d_ws, size_t ws_size,
                              hipStream_t stream) {
    const float* hidden = (const float*)d_in[0];
    const int*   mask   = (const int*)d_in[1];
    const float* W1     = (const float*)d_in[2];
    const float* b1     = (const float*)d_in[3];
    const float* W2     = (const float*)d_in[4];
    const float* b2     = (const float*)d_in[5];
    float* out = (float*)d_out;

    float* ws = (float*)d_ws;
    float* qbuf  = ws;                         // 8192*64
    float* kbuf  = qbuf + (long)NB * SEQL * DD; // 8192*64
    float* bqbuf = kbuf + (long)NB * SEQL * DD; // 8192*12
    float* bkbuf = bqbuf + (long)NB * SEQL * NH;

    k1_seq_rope_bias<<<512, 128, 0, stream>>>(hidden, W1, b1, W2, b2,
                                              qbuf, kbuf, bqbuf, bkbuf);
    k2_logits<<<dim3(16, 8, 8), 256, 0, stream>>>(qbuf, kbuf, bqbuf, bkbuf, mask, out);
}

// Round 3
// 132.177 us; speedup vs baseline: 1.2070x; 1.2070x over previous
//
#include <hip/hip_runtime.h>
#include <math.h>

#define HDIM 768
#define DD 64
#define SEQL 1024
#define NH 12
#define NB 8

typedef float f32x4 __attribute__((ext_vector_type(4)));

// ---------------- Kernel 1: seq = hidden@W1+b1, RoPE(q,k), bias = seq@W2+b2 ----------------
// 512 blocks x 128 threads; each block does 16 rows of the 8192-row problem.
__global__ __launch_bounds__(128) void k1_seq_rope_bias(
    const float* __restrict__ hidden, const float* __restrict__ W1,
    const float* __restrict__ b1, const float* __restrict__ W2,
    const float* __restrict__ b2,
    float* __restrict__ qo, float* __restrict__ ko,
    float* __restrict__ bqo, float* __restrict__ bko)
{
    __shared__ float hs[16 * HDIM];   // 48 KB: 16 hidden rows
    __shared__ float sq[16][132];     // seq tile (pad 132 for banks)
    const int tid = threadIdx.x;
    const long row0 = (long)blockIdx.x * 16;

    // stage 16 hidden rows (coalesced float4)
    const float4* src = (const float4*)(hidden + row0 * HDIM);
    float4* hdst = (float4*)hs;
    #pragma unroll
    for (int t = 0; t < 24; ++t)
        hdst[tid + t * 128] = src[tid + t * 128];
    __syncthreads();

    // GEMM: thread = 4 rows x 4 cols. cx in [0,32) -> cols 4cx.. ; ry in [0,4) -> rows 4ry..
    const int cx = tid & 31;
    const int ry = tid >> 5;
    const float4 bias1 = ((const float4*)b1)[cx];
    float4 acc[4];
    #pragma unroll
    for (int r = 0; r < 4; ++r) acc[r] = bias1;

    for (int k4 = 0; k4 < HDIM / 4; ++k4) {
        float4 w[4];
        #pragma unroll
        for (int kk = 0; kk < 4; ++kk)
            w[kk] = *(const float4*)(W1 + (k4 * 4 + kk) * 128 + cx * 4);
        #pragma unroll
        for (int r = 0; r < 4; ++r) {
            float4 hv = *(const float4*)(hs + (ry * 4 + r) * HDIM + k4 * 4);
            acc[r].x = fmaf(hv.x, w[0].x, fmaf(hv.y, w[1].x, fmaf(hv.z, w[2].x, fmaf(hv.w, w[3].x, acc[r].x))));
            acc[r].y = fmaf(hv.x, w[0].y, fmaf(hv.y, w[1].y, fmaf(hv.z, w[2].y, fmaf(hv.w, w[3].y, acc[r].y))));
            acc[r].z = fmaf(hv.x, w[0].z, fmaf(hv.y, w[1].z, fmaf(hv.z, w[2].z, fmaf(hv.w, w[3].z, acc[r].z))));
            acc[r].w = fmaf(hv.x, w[0].w, fmaf(hv.y, w[1].w, fmaf(hv.z, w[2].w, fmaf(hv.w, w[3].w, acc[r].w))));
        }
    }
    #pragma unroll
    for (int r = 0; r < 4; ++r)
        *(float4*)&sq[ry * 4 + r][cx * 4] = acc[r];
    __syncthreads();

    // bias: 16 rows x 24 outputs, dot over 128
    for (int idx = tid; idx < 16 * 24; idx += 128) {
        int r = idx / 24, jj = idx - r * 24;
        float s = b2[jj];
        #pragma unroll 16
        for (int c = 0; c < 128; ++c)
            s = fmaf(sq[r][c], W2[c * 24 + jj], s);
        long grow = row0 + r;
        if (jj & 1) bko[grow * NH + (jj >> 1)] = s;
        else        bqo[grow * NH + (jj >> 1)] = s;
    }

    // RoPE: 16 rows x 32 pairs, q and k share sincos
    for (int idx = tid; idx < 16 * 32; idx += 128) {
        int r = idx >> 5, p = idx & 31;
        long grow = row0 + r;
        int pos = (int)(grow & (SEQL - 1));
        float inv = __expf((float)p * -0.28782313662425576f); // 10000^(-p/32)
        float ang = (float)pos * inv;
        float sn, cs;
        __sincosf(ang, &sn, &cs);
        long base = grow * DD;
        float x0 = sq[r][2 * p], x1 = sq[r][2 * p + 1];
        qo[base + 2 * p]     = x0 * cs - x1 * sn;
        qo[base + 2 * p + 1] = x1 * cs + x0 * sn;
        float y0 = sq[r][DD + 2 * p], y1 = sq[r][DD + 2 * p + 1];
        ko[base + 2 * p]     = y0 * cs - y1 * sn;
        ko[base + 2 * p + 1] = y1 * cs + y0 * sn;
    }
}

// ---------------- Kernel 2: logits[b,h,m,n] = q.k/8 + bq[h,m] + bk[h,n] - tri - mask ----------------
// grid (16 n-tiles, 8 m-tiles, 8 b) x 256 threads. Tile 128(m) x 64(n), qk computed once, 12 heads fanned out.
// Micro-tile: thread owns rows m = tm+16i (i<8) and 4 CONSECUTIVE cols n = 4*tn+j -> float4 stores,
// 16 tn-lanes cover 256B contiguous per row.
__global__ __launch_bounds__(256, 2) void k2_logits(
    const float* __restrict__ q, const float* __restrict__ kmat,
    const float* __restrict__ bq, const float* __restrict__ bk,
    const int* __restrict__ mask, float* __restrict__ out)
{
    __shared__ float qs[128][68];  // rows read tm-broadcast: pad 68 conflict-free
    __shared__ float ks[64][65];   // rows read 4*tn+j: pad 65 -> bank base = row mod 32 -> 2-way (free)
    __shared__ float bqs[128][13]; // pad 13: 13*(tm+16i) distinct banks
    __shared__ float bks[64][13];  // pad 13: 13*4*tn mod 32 cycles 8 -> 2-way (free)
    const int tid = threadIdx.x;
    const int b = blockIdx.z;
    const int m0 = blockIdx.y * 128;
    const int n0 = blockIdx.x * 64;

    const float4* qsrc = (const float4*)(q + ((long)b * SEQL + m0) * DD);
    #pragma unroll
    for (int t = 0; t < 8; ++t) {
        int idx = tid + t * 256;
        *(float4*)&qs[idx >> 4][(idx & 15) * 4] = qsrc[idx];
    }
    const float4* ksrc = (const float4*)(kmat + ((long)b * SEQL + n0) * DD);
    #pragma unroll
    for (int t = 0; t < 4; ++t) {
        int idx = tid + t * 256;
        *(float4*)&ks[idx >> 4][(idx & 15) * 4] = ksrc[idx];
    }
    const float* bqg = bq + (long)(b * SEQL + m0) * NH;
    #pragma unroll
    for (int t = 0; t < 6; ++t) {
        int idx = tid + t * 256;  // < 1536, coalesced global read
        bqs[idx / 12][idx % 12] = bqg[idx];
    }
    const float* bkg = bk + (long)(b * SEQL + n0) * NH;
    #pragma unroll
    for (int t = 0; t < 3; ++t) {
        int idx = tid + t * 256;  // < 768
        bks[idx / 12][idx % 12] = bkg[idx];
    }
    __syncthreads();

    const int tm = tid >> 4;  // m = tm + 16*i  (i<8)
    const int tn = tid & 15;  // n = 4*tn + j   (j<4, consecutive)
    float acc[8][4];
    #pragma unroll
    for (int i = 0; i < 8; ++i)
        #pragma unroll
        for (int j = 0; j < 4; ++j) acc[i][j] = 0.f;

    #pragma unroll
    for (int k4 = 0; k4 < 16; ++k4) {
        float4 kv[4];
        #pragma unroll
        for (int j = 0; j < 4; ++j)
            kv[j] = *(const float4*)&ks[4 * tn + j][k4 * 4];
        #pragma unroll
        for (int i = 0; i < 8; ++i) {
            float4 qv = *(const float4*)&qs[tm + 16 * i][k4 * 4];
            #pragma unroll
            for (int j = 0; j < 4; ++j)
                acc[i][j] = fmaf(qv.x, kv[j].x, fmaf(qv.y, kv[j].y,
                             fmaf(qv.z, kv[j].z, fmaf(qv.w, kv[j].w, acc[i][j]))));
        }
    }

    // masks + scale + causal tri, folded into acc
    int mm[8];
    #pragma unroll
    for (int i = 0; i < 8; ++i) mm[i] = mask[b * SEQL + m0 + tm + 16 * i];
    const int4 mn4 = *(const int4*)(mask + b * SEQL + n0 + 4 * tn);
    int mn[4] = {mn4.x, mn4.y, mn4.z, mn4.w};
    #pragma unroll
    for (int i = 0; i < 8; ++i) {
        int m = m0 + tm + 16 * i;
        #pragma unroll
        for (int j = 0; j < 4; ++j) {
            int n = n0 + 4 * tn + j;
            float v = acc[i][j] * 0.125f;
            if (m > n) v -= 1e12f;
            if (!(mm[i] && mn[j])) v = -INFINITY;
            acc[i][j] = v;
        }
    }

    // fan out to 12 heads, float4 non-temporal stores
    #pragma unroll 1
    for (int h = 0; h < NH; ++h) {
        float bkv[4];
        #pragma unroll
        for (int j = 0; j < 4; ++j)
            bkv[j] = bks[4 * tn + j][h];
        float* ob = out + ((long)(b * NH + h) * SEQL + m0) * SEQL + n0 + 4 * tn;
        #pragma unroll
        for (int i = 0; i < 8; ++i) {
            float bqv = bqs[tm + 16 * i][h];
            f32x4 v;
            v.x = acc[i][0] + bqv + bkv[0];
            v.y = acc[i][1] + bqv + bkv[1];
            v.z = acc[i][2] + bqv + bkv[2];
            v.w = acc[i][3] + bqv + bkv[3];
            __builtin_nontemporal_store(v, (f32x4*)(ob + (long)(tm + 16 * i) * SEQL));
        }
    }
}

extern "C" void kernel_launch(void* const* d_in, const int* in_sizes, int n_in,
                              void* d_out, int out_size, void* d_ws, size_t ws_size,
                              hipStream_t stream) {
    const float* hidden = (const float*)d_in[0];
    const int*   mask   = (const int*)d_in[1];
    const float* W1     = (const float*)d_in[2];
    const float* b1     = (const float*)d_in[3];
    const float* W2     = (const float*)d_in[4];
    const float* b2     = (const float*)d_in[5];
    float* out = (float*)d_out;

    float* ws = (float*)d_ws;
    float* qbuf  = ws;                          // 8192*64
    float* kbuf  = qbuf + (long)NB * SEQL * DD; // 8192*64
    float* bqbuf = kbuf + (long)NB * SEQL * DD; // 8192*12
    float* bkbuf = bqbuf + (long)NB * SEQL * NH;

    k1_seq_rope_bias<<<512, 128, 0, stream>>>(hidden, W1, b1, W2, b2,
                                              qbuf, kbuf, bqbuf, bkbuf);
    k2_logits<<<dim3(16, 8, 8), 256, 0, stream>>>(qbuf, kbuf, bqbuf, bkbuf, mask, out);
}